// Round 4
// baseline (224.059 us; speedup 1.0000x reference)
//
#include <hip/hip_runtime.h>

// IGANN: per-feature 2-layer MLPs (1->16->16->1), summed over 256 features + linear term.
// R26 = R25 with x LDS staging ELIMINATED (numerics bit-identical):
//   - Ledger: output path (null), occupancy 6->8 (-2.6), XCD pinning (null). Budget
//     arithmetic (13-dispatch iteration, 42.5us fill, ~10 tiny restores) puts igann
//     at ~35-42us vs a ~10us floor -> the untried mechanism is the block-wide
//     stage->syncthreads->compute serialization on the cold-HBM x tile.
//   - Key observation: lane (g,r), tile t only needs x[w*64+16t+r][f0..f0+15] = 64
//     contiguous bytes = exactly the A-fragment source. Load DIRECTLY from global:
//     4 g-groups issue duplicate addresses (coalescer merges); one 64-B line per row
//     serves all 4 granules (L1-hot after q=0).
//   - x granules double-buffered in registers through the fi-loop; granule-0 loads
//     issued BEFORE weight staging so they fly under the (L2-hot, small) weight
//     barrier. No block-wide wait on x at all; per-wave self-paced via vmcnt.
//   - lin term computed in-loop from the same registers (all lanes compute, g==0
//     lanes deposit rows w*64+16t+r into lins[] -- race-free, same-wave consumption).
//   - LDS 19456 -> 12544 B; hand VGPR ~58 (< 64 cap of launch_bounds(256,8)).

typedef float    f32x4 __attribute__((ext_vector_type(4)));
typedef _Float16 f16x4 __attribute__((ext_vector_type(4)));
typedef __fp16   pk16x2 __attribute__((ext_vector_type(2)));

__device__ __forceinline__ f16x4 cvt4(f32x4 v) {
    pk16x2 lo = __builtin_amdgcn_cvt_pkrtz(v[0], v[1]);
    pk16x2 hi = __builtin_amdgcn_cvt_pkrtz(v[2], v[3]);
    union { unsigned u[2]; f16x4 h; } un;
    un.u[0] = __builtin_bit_cast(unsigned, lo);
    un.u[1] = __builtin_bit_cast(unsigned, hi);
    return un.h;
}

__device__ __forceinline__ f16x4 relu_h(f16x4 v) {
    f16x4 z = {};
    return __builtin_elementwise_max(v, z);
}

__device__ __forceinline__ f32x4 relu_f(f32x4 v) {
    f32x4 z = {0.f, 0.f, 0.f, 0.f};
    return __builtin_elementwise_max(v, z);
}

#define FCHUNK 16   // features per block (16 groups of 16 = 256)
#define BATCH  32768

__global__ __launch_bounds__(256, 8) void igann_kernel(
    const float* __restrict__ x,  const float* __restrict__ la,
    const float* __restrict__ bb, const float* __restrict__ W1,
    const float* __restrict__ b1, const float* __restrict__ W2,
    const float* __restrict__ b2, const float* __restrict__ W3,
    const float* __restrict__ b3, float* __restrict__ ws)
{
    const int tid = threadIdx.x;
    const int l   = tid & 63;     // lane
    const int w   = tid >> 6;     // wave in block (0..3)
    const int r   = l & 15;       // MFMA row m (A) / col n (D)
    const int g   = l >> 4;       // k-group
    const int g4  = g * 4;

    // XCD-pinning swizzle (kept from R25; harmless): rb%8 == bid%8
    const int bid = blockIdx.x;
    const int rb  = (bid & 7) + (((bid >> 3) & 15) << 3);   // 0..127
    const int fg  = bid >> 7;                               // 0..15
    const int f0  = fg * FCHUNK;
    const int rowbase = rb * 256;

    // w2s [f][n][granule^((n>>2)&3)][4] f16 : 8192 B, conflict-free bfrag reads
    // wbs [f][g][w1 x4 | b1 x4] f16         : 1024 B, dead after loop -> sums overlay
    // bws [f][n] -> (b2, w3) float2         : 2048 B
    // lins[row]                             : 1024 B
    __shared__ _Float16 w2s[FCHUNK * 16 * 16];
    __shared__ float    wbs_sums[256];          // union: wbs (f16 view) / sums (f32)
    __shared__ float2   bws[FCHUNK * 16];
    __shared__ float    lins[256];
    _Float16* wbs  = (_Float16*)wbs_sums;
    float*    sums = wbs_sums;                  // -> 12544 B total

    // ---- issue granule-0 x loads FIRST (fly under weight staging + barrier) ----
    // lane (w,r,t): row = rowbase + w*64 + t*16 + r; needs x[row][f0 + 4q + u].
    // Address independent of g -> 4-fold duplicate, merged by the coalescer.
    const float* xp0 = x + (size_t)(rowbase + w * 64 + r) * 256 + f0;
    f32x4 xr[4];
    #pragma unroll
    for (int t = 0; t < 4; ++t)
        xr[t] = *(const f32x4*)(xp0 + t * 4096);            // granule 0, tile t

    // ---- stage W2 (thread tid owns (f,n)=(tid>>4, tid&15)) ----
    {
        const int f = tid >> 4, n = tid & 15;
        const int sw = (n >> 2) & 3;
        const float* src = W2 + ((size_t)(f0 + f) * 16 + n) * 16;
        _Float16* dst = w2s + (f * 16 + n) * 16;
        #pragma unroll
        for (int q = 0; q < 4; ++q) {
            f32x4 v = *(const f32x4*)(src + q * 4);
            *(f16x4*)(dst + ((q ^ sw) & 3) * 4) = cvt4(v);
        }
    }
    // ---- stage interleaved W1|b1 (scalar f16 stores; thread tid owns (f,k)) ----
    {
        const int f = tid >> 4, k = tid & 15;
        const int base = f * 32 + (k >> 2) * 8 + (k & 3);   // [f][g][lo4|hi4]
        wbs[base]     = (_Float16)W1[(size_t)(f0 + f) * 16 + k];
        wbs[base + 4] = (_Float16)b1[(size_t)(f0 + f) * 16 + k];
    }
    // ---- stage (b2, w3) float2 pairs ----
    {
        const int f = tid >> 4, n = tid & 15;
        bws[tid] = make_float2(b2[(size_t)(f0 + f) * 16 + n],
                               W3[(size_t)(f0 + f) * 16 + n]);
    }
    __syncthreads();

    const _Float16* w2p = w2s + r * 16 + ((g ^ ((r >> 2) & 3)) & 3) * 4;

    f32x4 acc[4];     // [tile][j]: D row g4+j (batch row within tile), col r (channel)
    #pragma unroll
    for (int t = 0; t < 4; ++t) acc[t] = (f32x4){0.f, 0.f, 0.f, 0.f};
    float lin4[4] = {0.f, 0.f, 0.f, 0.f};

    #pragma unroll
    for (int q = 0; q < 4; ++q) {              // feature granules (4 features each)
        f16x4 xh[4];
        #pragma unroll
        for (int t = 0; t < 4; ++t) xh[t] = cvt4(xr[t]);    // waits on xr loads
        if (q < 3) {
            #pragma unroll
            for (int t = 0; t < 4; ++t)                      // next granule in flight
                xr[t] = *(const f32x4*)(xp0 + t * 4096 + (q + 1) * 4);
        }
        // lin partials (all lanes compute; g==0 deposits later). la uniform -> s_load.
        #pragma unroll
        for (int t = 0; t < 4; ++t)
            #pragma unroll
            for (int u = 0; u < 4; ++u)
                lin4[t] = fmaf((float)xh[t][u], la[f0 + q * 4 + u], lin4[t]);

        #pragma unroll
        for (int u = 0; u < 4; ++u) {
            const int f = q * 4 + u;
            // adjacent f16x4 reads (8 B apart) -> ds_read2_b64
            f16x4 w1h   = *(const f16x4*)(wbs + f * 32 + g * 8);
            f16x4 b1h   = *(const f16x4*)(wbs + f * 32 + g * 8 + 4);
            f16x4 bfrag = *(const f16x4*)(w2p + f * 256);
            const float2 bw = bws[f * 16 + r];          // one ds_read_b64
            const f32x4 cinit = {bw.x, bw.x, bw.x, bw.x};   // b2 folded into MFMA C
            const f32x4 w3k4  = {bw.y, bw.y, bw.y, bw.y};

            #pragma unroll
            for (int t = 0; t < 4; ++t) {
                const _Float16 s = xh[t][u];
                f16x4 xb = {s, s, s, s};
                f16x4 h = relu_h(xb * w1h + b1h);       // v_pk_fma_f16 + v_pk_max_f16
                f32x4 d = __builtin_amdgcn_mfma_f32_16x16x16f16(h, bfrag, cinit, 0, 0, 0);
                acc[t] = __builtin_elementwise_fma(relu_f(d), w3k4, acc[t]);
            }
        }
    }

    __syncthreads();   // all waves done reading wbs before sums overlays it

    // ---- deposit lin partials: g==0 lanes own rows w*64 + t*16 + r (race-free) ----
    if (g == 0) {
        #pragma unroll
        for (int t = 0; t < 4; ++t)
            lins[w * 64 + t * 16 + r] = lin4[t];
    }
    // ---- channel reduce (lane bits 0..3); r==0 lanes park sums in LDS ----
    #pragma unroll
    for (int t = 0; t < 4; ++t)
        #pragma unroll
        for (int j = 0; j < 4; ++j) {
            float v = acc[t][j];
            v += __shfl_xor(v, 1, 64);
            v += __shfl_xor(v, 2, 64);
            v += __shfl_xor(v, 4, 64);
            v += __shfl_xor(v, 8, 64);
            if (r == 0)
                sums[w * 64 + t * 16 + g4 + j] = v;   // 4 lanes, stride-16B: bank-clean
        }
    __syncthreads();

    // ---- b3 partial + coalesced store ----
    float b3s = 0.f;
    #pragma unroll
    for (int c = 0; c < FCHUNK; ++c) b3s += b3[f0 + c];   // uniform -> s_loads
    ws[(size_t)fg * BATCH + rowbase + tid] = sums[tid] + lins[tid] + b3s;
}

__global__ __launch_bounds__(128) void igann_reduce(
    const float* __restrict__ ws, const float* __restrict__ bb,
    float* __restrict__ out)
{
    const int i = blockIdx.x * 128 + threadIdx.x;
    float s = bb[0];
    #pragma unroll
    for (int gq = 0; gq < 16; ++gq)
        s += ws[(size_t)gq * BATCH + i];    // coalesced across threads; L2-hot
    out[i] = s;
}

extern "C" void kernel_launch(void* const* d_in, const int* in_sizes, int n_in,
                              void* d_out, int out_size, void* d_ws, size_t ws_size,
                              hipStream_t stream) {
    const float* x  = (const float*)d_in[0];
    const float* la = (const float*)d_in[1];
    const float* bb = (const float*)d_in[2];
    const float* W1 = (const float*)d_in[3];
    const float* b1 = (const float*)d_in[4];
    const float* W2 = (const float*)d_in[5];
    const float* b2 = (const float*)d_in[6];
    const float* W3 = (const float*)d_in[7];
    const float* b3 = (const float*)d_in[8];
    float* out = (float*)d_out;
    float* ws  = (float*)d_ws;

    dim3 grid(2048), block(256);   // 2048 = 8 XCD groups x 16 rb x 16 fg (swizzled)
    hipLaunchKernelGGL(igann_kernel, grid, block, 0, stream,
                       x, la, bb, W1, b1, W2, b2, W3, b3, ws);
    hipLaunchKernelGGL(igann_reduce, dim3(256), dim3(128), 0, stream,
                       ws, bb, out);
}

// Round 6
// 110.922 us; speedup vs baseline: 2.0200x; 2.0200x over previous
//
#include <hip/hip_runtime.h>

// IGANN: per-feature 2-layer MLPs (1->16->16->1), summed over 256 features + linear term.
// R28 = R27 with the asm operand TYPO fixed (R27's theory untested, not falsified):
//   - R27 failed absmax=241: second v_pk_fma_f32 read %3 (relu lo-pair) where it
//     needed %2 (w3 pair) -> acc_hi += relu_hi * relu_lo. One-character bug.
//   - R28 splits the two pk-fmas into separate asm statements with named operands
//     so the pairing is auditable: acc_lo += relu_lo * w3p; acc_hi += relu_hi * w3p.
//   - Mechanism under test (from R26's counters: igann is VALU-issue-bound,
//     VALUBusy-time ~16.8us absolute): epilogue scale-accumulate 4x v_fma_f32 ->
//     2x v_pk_fma_f32 (VOP3P packed f32: 2 FMA per 2-cy issue; no v_pk_max_f32
//     exists, relu stays 4x v_max_f32).
//   - Everything else R25 (best: 105.76): LDS swizzled xs/w2s, wbs/sums overlay,
//     19456B LDS, launch_bounds(256,8) = 8 blocks/CU, XCD-pinning swizzle,
//     partial-sum ws + reduce kernel.

typedef float    f32x4 __attribute__((ext_vector_type(4)));
typedef float    f32x2 __attribute__((ext_vector_type(2)));
typedef _Float16 f16x4 __attribute__((ext_vector_type(4)));
typedef __fp16   pk16x2 __attribute__((ext_vector_type(2)));

__device__ __forceinline__ f16x4 cvt4(f32x4 v) {
    pk16x2 lo = __builtin_amdgcn_cvt_pkrtz(v[0], v[1]);
    pk16x2 hi = __builtin_amdgcn_cvt_pkrtz(v[2], v[3]);
    union { unsigned u[2]; f16x4 h; } un;
    un.u[0] = __builtin_bit_cast(unsigned, lo);
    un.u[1] = __builtin_bit_cast(unsigned, hi);
    return un.h;
}

__device__ __forceinline__ f16x4 relu_h(f16x4 v) {
    f16x4 z = {};
    return __builtin_elementwise_max(v, z);
}

__device__ __forceinline__ f32x4 relu_f(f32x4 v) {
    f32x4 z = {0.f, 0.f, 0.f, 0.f};
    return __builtin_elementwise_max(v, z);
}

#define FCHUNK 16   // features per block (16 groups of 16 = 256)
#define BATCH  32768

__global__ __launch_bounds__(256, 8) void igann_kernel(
    const float* __restrict__ x,  const float* __restrict__ la,
    const float* __restrict__ bb, const float* __restrict__ W1,
    const float* __restrict__ b1, const float* __restrict__ W2,
    const float* __restrict__ b2, const float* __restrict__ W3,
    const float* __restrict__ b3, float* __restrict__ ws)
{
    const int tid = threadIdx.x;
    const int l   = tid & 63;     // lane
    const int w   = tid >> 6;     // wave in block (0..3)
    const int r   = l & 15;       // MFMA row m (A) / col n (D)
    const int g   = l >> 4;       // k-group
    const int g4  = g * 4;

    // XCD-pinning swizzle: all 16 fg-blocks of an rb satisfy bid%8 == rb%8
    const int bid = blockIdx.x;
    const int rb  = (bid & 7) + (((bid >> 3) & 15) << 3);   // 0..127
    const int fg  = bid >> 7;                               // 0..15
    const int f0  = fg * FCHUNK;
    const int rowbase = rb * 256;

    // xs  [row][granule^((row>>2)&3)][4]  : 8192 B, conflict-free b64 frag reads
    // w2s [f][n][granule^((n>>2)&3)][4]   : 8192 B, conflict-free bfrag reads
    // wbs [f][g][w1 x4 | b1 x4] f16       : 1024 B, dead after loop -> sums overlay
    // bws [f][n] -> (b2, w3) float2       : 2048 B
    __shared__ _Float16 xs [256 * 16];
    __shared__ _Float16 w2s[FCHUNK * 16 * 16];
    __shared__ float    wbs_sums[256];          // union: wbs (f16 view) / sums (f32)
    __shared__ float2   bws[FCHUNK * 16];
    _Float16* wbs  = (_Float16*)wbs_sums;
    float*    sums = wbs_sums;                  // -> 19456 B total: 8 blocks/CU

    // ---- stage x slice (coalesced: 4 lanes cover one 64-B row-slice) ----
    {
        const int rr  = tid >> 2;         // 0..63
        const int c4g = tid & 3;          // granule 0..3
        const int sw  = (rr >> 2) & 3;    // (row>>2)&3 — it*64 doesn't touch bits 2..3
        #pragma unroll
        for (int it = 0; it < 4; ++it) {
            const int row = it * 64 + rr;
            f32x4 v = *(const f32x4*)(x + (size_t)(rowbase + row) * 256 + f0 + c4g * 4);
            *(f16x4*)(xs + row * 16 + ((c4g ^ sw) & 3) * 4) = cvt4(v);
        }
    }
    // ---- stage W2 (thread tid owns (f,n)=(tid>>4, tid&15)) ----
    {
        const int f = tid >> 4, n = tid & 15;
        const int sw = (n >> 2) & 3;
        const float* src = W2 + ((size_t)(f0 + f) * 16 + n) * 16;
        _Float16* dst = w2s + (f * 16 + n) * 16;
        #pragma unroll
        for (int q = 0; q < 4; ++q) {
            f32x4 v = *(const f32x4*)(src + q * 4);
            *(f16x4*)(dst + ((q ^ sw) & 3) * 4) = cvt4(v);
        }
    }
    // ---- stage interleaved W1|b1 (scalar f16 stores; thread tid owns (f,k)) ----
    {
        const int f = tid >> 4, k = tid & 15;
        const int base = f * 32 + (k >> 2) * 8 + (k & 3);   // [f][g][lo4|hi4]
        wbs[base]     = (_Float16)W1[(size_t)(f0 + f) * 16 + k];
        wbs[base + 4] = (_Float16)b1[(size_t)(f0 + f) * 16 + k];
    }
    // ---- stage (b2, w3) float2 pairs ----
    {
        const int f = tid >> 4, n = tid & 15;
        bws[tid] = make_float2(b2[(size_t)(f0 + f) * 16 + n],
                               W3[(size_t)(f0 + f) * 16 + n]);
    }
    __syncthreads();

    const _Float16* xw  = xs + (w * 64 + r) * 16;
    const int       xsw = ((w * 64 + r) >> 2) & 3;          // per-lane swizzle sel
    const _Float16* w2p = w2s + r * 16 + ((g ^ ((r >> 2) & 3)) & 3) * 4;

    // acc as f32x2 pairs for v_pk_fma_f32: acc2[t][h] covers D comps j = h*2 + c
    f32x2 acc2[4][2];
    #pragma unroll
    for (int t = 0; t < 4; ++t) {
        acc2[t][0] = (f32x2){0.f, 0.f};
        acc2[t][1] = (f32x2){0.f, 0.f};
    }

    for (int fi = 0; fi < FCHUNK; fi += 4) {   // rolled: keeps register pressure down
        const int xoff = (((fi >> 2) ^ xsw) & 3) * 4;
        f16x4 xv[4];
        #pragma unroll
        for (int t = 0; t < 4; ++t)
            xv[t] = *(const f16x4*)(xw + t * 256 + xoff);    // t*16 rows * 16 f16

        #pragma unroll
        for (int u = 0; u < 4; ++u) {
            const int f = fi + u;
            // adjacent f16x4 reads (8 B apart) -> ds_read2_b64
            f16x4 w1h   = *(const f16x4*)(wbs + f * 32 + g * 8);
            f16x4 b1h   = *(const f16x4*)(wbs + f * 32 + g * 8 + 4);
            f16x4 bfrag = *(const f16x4*)(w2p + f * 256);
            const float2 bw = bws[f * 16 + r];          // one ds_read_b64
            const f32x4 cinit = {bw.x, bw.x, bw.x, bw.x};   // b2 folded into MFMA C
            f32x2 w3p;                                   // {w3, w3} pair, reused 4x
            w3p[0] = bw.y; w3p[1] = bw.y;

            #pragma unroll
            for (int t = 0; t < 4; ++t) {
                const _Float16 s = xv[t][u];
                f16x4 xb = {s, s, s, s};
                f16x4 h = relu_h(xb * w1h + b1h);       // v_pk_fma_f16 + v_pk_max_f16
                f32x4 d = __builtin_amdgcn_mfma_f32_16x16x16f16(h, bfrag, cinit, 0, 0, 0);
                union { f32x4 v; f32x2 h2[2]; } ru;
                ru.v = relu_f(d);                        // 4x v_max_f32 (no pk max f32)
                // acc += relu(d) * w3 : 2x v_pk_fma_f32 (2 FMA per 2-cy issue).
                // Named operands; each statement self-contained and auditable.
                asm("v_pk_fma_f32 %[a], %[x], %[y], %[a]"
                    : [a] "+v"(acc2[t][0])
                    : [x] "v"(ru.h2[0]), [y] "v"(w3p));
                asm("v_pk_fma_f32 %[a], %[x], %[y], %[a]"
                    : [a] "+v"(acc2[t][1])
                    : [x] "v"(ru.h2[1]), [y] "v"(w3p));
            }
        }
    }

    __syncthreads();   // all waves done reading wbs before sums overlays it

    // ---- channel reduce (lane bits 0..3); r==0 lanes park sums in LDS ----
    #pragma unroll
    for (int t = 0; t < 4; ++t)
        #pragma unroll
        for (int h = 0; h < 2; ++h)
            #pragma unroll
            for (int c = 0; c < 2; ++c) {
                float v = acc2[t][h][c];
                v += __shfl_xor(v, 1, 64);
                v += __shfl_xor(v, 2, 64);
                v += __shfl_xor(v, 4, 64);
                v += __shfl_xor(v, 8, 64);
                if (r == 0)
                    sums[w * 64 + t * 16 + g4 + h * 2 + c] = v;   // bank-clean
            }
    __syncthreads();

    // ---- linear term + b3 partial folded in; ONE coalesced store per row ----
    float b3s = 0.f;
    #pragma unroll
    for (int c = 0; c < FCHUNK; ++c) b3s += b3[f0 + c];   // uniform -> s_loads
    float lin = 0.f;
    {
        const int swe = (tid >> 2) & 3;
        #pragma unroll
        for (int gq = 0; gq < 4; ++gq) {
            f16x4 xv4 = *(const f16x4*)(xs + tid * 16 + ((gq ^ swe) & 3) * 4);
            #pragma unroll
            for (int e = 0; e < 4; ++e)
                lin = fmaf((float)xv4[e], la[f0 + gq * 4 + e], lin);  // la uniform
        }
    }
    ws[(size_t)fg * BATCH + rowbase + tid] = sums[tid] + lin + b3s;
}

__global__ __launch_bounds__(128) void igann_reduce(
    const float* __restrict__ ws, const float* __restrict__ bb,
    float* __restrict__ out)
{
    const int i = blockIdx.x * 128 + threadIdx.x;
    float s = bb[0];
    #pragma unroll
    for (int gq = 0; gq < 16; ++gq)
        s += ws[(size_t)gq * BATCH + i];    // coalesced across threads; L2-hot
    out[i] = s;
}

extern "C" void kernel_launch(void* const* d_in, const int* in_sizes, int n_in,
                              void* d_out, int out_size, void* d_ws, size_t ws_size,
                              hipStream_t stream) {
    const float* x  = (const float*)d_in[0];
    const float* la = (const float*)d_in[1];
    const float* bb = (const float*)d_in[2];
    const float* W1 = (const float*)d_in[3];
    const float* b1 = (const float*)d_in[4];
    const float* W2 = (const float*)d_in[5];
    const float* b2 = (const float*)d_in[6];
    const float* W3 = (const float*)d_in[7];
    const float* b3 = (const float*)d_in[8];
    float* out = (float*)d_out;
    float* ws  = (float*)d_ws;

    dim3 grid(2048), block(256);   // 2048 = 8 XCD groups x 16 rb x 16 fg (swizzled)
    hipLaunchKernelGGL(igann_kernel, grid, block, 0, stream,
                       x, la, bb, W1, b1, W2, b2, W3, b3, ws);
    hipLaunchKernelGGL(igann_reduce, dim3(256), dim3(128), 0, stream,
                       ws, bb, out);
}

// Round 7
// 109.832 us; speedup vs baseline: 2.0400x; 1.0099x over previous
//
#include <hip/hip_runtime.h>

// IGANN: per-feature 2-layer MLPs (1->16->16->1), summed over 256 features + linear term.
// R29 = R25 inner math VERBATIM (best: 105.76; R28's pk-fma asm reverted — it regressed,
// falsifying "VALU-issue-bound") + double-buffered 512-row blocks:
//   - Honest floor recount: R25 loop = ~768 VALU/thread -> ~5us chip-wide; igann ~26us
//     by window subtraction -> the gap is the UNOVERLAPPED stage->barrier->compute
//     serialization + 2048-short-block ramp. R26 attacked the barrier but broke the
//     load pattern; this keeps R25's coalesced staging and adds overlap instead.
//   - Each block: 512 rows (two 256-row halves), grid 1024 = 64 rbb x 16 fg.
//     Pipeline: stage A -> barrier -> ISSUE B global loads (regs) -> compute A
//     (B's HBM latency hides under A's MFMA/VALU) -> reduce A -> cvt+write B to
//     xs[1] -> barrier -> compute B -> reduce B -> barrier -> lin+store both halves.
//   - LDS 29 KB (xs 2x8K dbuf, w2s 8K, wbs 1K, bws 2K, sums 2K separate — no overlay,
//     wbs must live through compute B) -> 5 blocks/CU by LDS, grid wants 4 -> one
//     residency round. launch_bounds(256,4): VGPR cap 128 (live set ~70).
//   - XCD pinning: rbb = bid&63, fg = bid>>6 -> all 16 fgs of an rbb share bid%8.
//   - Everything else R25: swizzled xs/w2s, ds_read2_b64 W1|b1, (b2,w3) float2,
//     b2-in-MFMA-C, partial-sum ws + reduce kernel.

typedef float    f32x4 __attribute__((ext_vector_type(4)));
typedef _Float16 f16x4 __attribute__((ext_vector_type(4)));
typedef __fp16   pk16x2 __attribute__((ext_vector_type(2)));

__device__ __forceinline__ f16x4 cvt4(f32x4 v) {
    pk16x2 lo = __builtin_amdgcn_cvt_pkrtz(v[0], v[1]);
    pk16x2 hi = __builtin_amdgcn_cvt_pkrtz(v[2], v[3]);
    union { unsigned u[2]; f16x4 h; } un;
    un.u[0] = __builtin_bit_cast(unsigned, lo);
    un.u[1] = __builtin_bit_cast(unsigned, hi);
    return un.h;
}

__device__ __forceinline__ f16x4 relu_h(f16x4 v) {
    f16x4 z = {};
    return __builtin_elementwise_max(v, z);
}

__device__ __forceinline__ f32x4 relu_f(f32x4 v) {
    f32x4 z = {0.f, 0.f, 0.f, 0.f};
    return __builtin_elementwise_max(v, z);
}

#define FCHUNK 16   // features per block (16 groups of 16 = 256)
#define BATCH  32768

__global__ __launch_bounds__(256, 4) void igann_kernel(
    const float* __restrict__ x,  const float* __restrict__ la,
    const float* __restrict__ bb, const float* __restrict__ W1,
    const float* __restrict__ b1, const float* __restrict__ W2,
    const float* __restrict__ b2, const float* __restrict__ W3,
    const float* __restrict__ b3, float* __restrict__ ws)
{
    const int tid = threadIdx.x;
    const int l   = tid & 63;     // lane
    const int w   = tid >> 6;     // wave in block (0..3)
    const int r   = l & 15;       // MFMA row m (A) / col n (D)
    const int g   = l >> 4;       // k-group
    const int g4  = g * 4;

    // XCD pinning: rbb = bid&63 -> all 16 fg-blocks of an rbb share bid%8.
    const int bid = blockIdx.x;
    const int rbb = bid & 63;                  // 512-row super-block (0..63)
    const int fg  = bid >> 6;                  // 0..15
    const int f0  = fg * FCHUNK;
    const int rowbase = rbb * 512;

    __shared__ _Float16 xs [2][256 * 16];      // 16384 B: double-buffered x halves
    __shared__ _Float16 w2s[FCHUNK * 16 * 16]; //  8192 B: [f][n][granule^((n>>2)&3)][4]
    __shared__ _Float16 wbs[FCHUNK * 4 * 8];   //  1024 B: [f][g][w1 x4 | b1 x4]
    __shared__ float2   bws[FCHUNK * 16];      //  2048 B: [f][n] -> (b2, w3)
    __shared__ float    sums[512];             //  2048 B  -> 29696 B total

    const int rr  = tid >> 2;         // 0..63
    const int c4g = tid & 3;          // granule 0..3
    const int sw  = (rr >> 2) & 3;    // row bits 2..3 (it*64, +256 don't touch them)
    const float* xsrc = x + (size_t)rowbase * 256 + f0 + c4g * 4;

    // ---- issue half-A global loads first (fly under weight staging) ----
    f32x4 xa[4];
    #pragma unroll
    for (int it = 0; it < 4; ++it)
        xa[it] = *(const f32x4*)(xsrc + (size_t)(it * 64 + rr) * 256);

    // ---- stage W2 (thread tid owns (f,n)=(tid>>4, tid&15)) ----
    {
        const int f = tid >> 4, n = tid & 15;
        const int swn = (n >> 2) & 3;
        const float* src = W2 + ((size_t)(f0 + f) * 16 + n) * 16;
        _Float16* dst = w2s + (f * 16 + n) * 16;
        #pragma unroll
        for (int q = 0; q < 4; ++q) {
            f32x4 v = *(const f32x4*)(src + q * 4);
            *(f16x4*)(dst + ((q ^ swn) & 3) * 4) = cvt4(v);
        }
    }
    // ---- stage interleaved W1|b1 ----
    {
        const int f = tid >> 4, k = tid & 15;
        const int base = f * 32 + (k >> 2) * 8 + (k & 3);   // [f][g][lo4|hi4]
        wbs[base]     = (_Float16)W1[(size_t)(f0 + f) * 16 + k];
        wbs[base + 4] = (_Float16)b1[(size_t)(f0 + f) * 16 + k];
    }
    // ---- stage (b2, w3) float2 pairs ----
    {
        const int f = tid >> 4, n = tid & 15;
        bws[tid] = make_float2(b2[(size_t)(f0 + f) * 16 + n],
                               W3[(size_t)(f0 + f) * 16 + n]);
    }
    // ---- write half A to xs[0] (compiler waits vmcnt on xa) ----
    #pragma unroll
    for (int it = 0; it < 4; ++it)
        *(f16x4*)(xs[0] + (it * 64 + rr) * 16 + ((c4g ^ sw) & 3) * 4) = cvt4(xa[it]);
    __syncthreads();

    // ---- issue half-B global loads; they drain under compute-A ----
    f32x4 xb4[4];
    #pragma unroll
    for (int it = 0; it < 4; ++it)
        xb4[it] = *(const f32x4*)(xsrc + (size_t)(256 + it * 64 + rr) * 256);

    const int       rw  = w * 64 + r;                       // wave's base row in half
    const int       xsw = (rw >> 2) & 3;                    // per-lane x swizzle sel
    const _Float16* w2p = w2s + r * 16 + ((g ^ ((r >> 2) & 3)) & 3) * 4;

    // ---- per-half compute + channel reduce (R25 math, bit-identical) ----
    auto compute_half = [&](const _Float16* xsb, float* sh) {
        const _Float16* xw = xsb + rw * 16;
        f32x4 acc[4];
        #pragma unroll
        for (int t = 0; t < 4; ++t) acc[t] = (f32x4){0.f, 0.f, 0.f, 0.f};

        for (int fi = 0; fi < FCHUNK; fi += 4) {
            const int xoff = (((fi >> 2) ^ xsw) & 3) * 4;
            f16x4 xv[4];
            #pragma unroll
            for (int t = 0; t < 4; ++t)
                xv[t] = *(const f16x4*)(xw + t * 256 + xoff);

            #pragma unroll
            for (int u = 0; u < 4; ++u) {
                const int f = fi + u;
                f16x4 w1h   = *(const f16x4*)(wbs + f * 32 + g * 8);
                f16x4 b1h   = *(const f16x4*)(wbs + f * 32 + g * 8 + 4);
                f16x4 bfrag = *(const f16x4*)(w2p + f * 256);
                const float2 bw = bws[f * 16 + r];
                const f32x4 cinit = {bw.x, bw.x, bw.x, bw.x};   // b2 in MFMA C
                const f32x4 w3k4  = {bw.y, bw.y, bw.y, bw.y};

                #pragma unroll
                for (int t = 0; t < 4; ++t) {
                    const _Float16 s = xv[t][u];
                    f16x4 xb = {s, s, s, s};
                    f16x4 h = relu_h(xb * w1h + b1h);
                    f32x4 d = __builtin_amdgcn_mfma_f32_16x16x16f16(h, bfrag, cinit, 0, 0, 0);
                    acc[t] = __builtin_elementwise_fma(relu_f(d), w3k4, acc[t]);
                }
            }
        }
        #pragma unroll
        for (int t = 0; t < 4; ++t)
            #pragma unroll
            for (int j = 0; j < 4; ++j) {
                float v = acc[t][j];
                v += __shfl_xor(v, 1, 64);
                v += __shfl_xor(v, 2, 64);
                v += __shfl_xor(v, 4, 64);
                v += __shfl_xor(v, 8, 64);
                if (r == 0)
                    sh[w * 64 + t * 16 + g4 + j] = v;   // 4 lanes, 16B stride: clean
            }
    };

    compute_half(xs[0], sums);          // half-B loads in flight underneath

    // ---- write half B to xs[1] (vmcnt wait on xb4 here, mostly drained) ----
    #pragma unroll
    for (int it = 0; it < 4; ++it)
        *(f16x4*)(xs[1] + (it * 64 + rr) * 16 + ((c4g ^ sw) & 3) * 4) = cvt4(xb4[it]);
    __syncthreads();

    compute_half(xs[1], sums + 256);
    __syncthreads();

    // ---- linear term + b3; two coalesced stores per thread ----
    float b3s = 0.f;
    #pragma unroll
    for (int c = 0; c < FCHUNK; ++c) b3s += b3[f0 + c];   // uniform -> s_loads
    const int swe = (tid >> 2) & 3;
    float lin0 = 0.f, lin1 = 0.f;
    #pragma unroll
    for (int gq = 0; gq < 4; ++gq) {
        const int off = tid * 16 + ((gq ^ swe) & 3) * 4;
        f16x4 a0 = *(const f16x4*)(xs[0] + off);
        f16x4 a1 = *(const f16x4*)(xs[1] + off);
        #pragma unroll
        for (int e = 0; e < 4; ++e) {
            const float lae = la[f0 + gq * 4 + e];        // uniform
            lin0 = fmaf((float)a0[e], lae, lin0);
            lin1 = fmaf((float)a1[e], lae, lin1);
        }
    }
    float* wsp = ws + (size_t)fg * BATCH + rowbase;
    wsp[tid]       = sums[tid]       + lin0 + b3s;
    wsp[256 + tid] = sums[256 + tid] + lin1 + b3s;
}

__global__ __launch_bounds__(128) void igann_reduce(
    const float* __restrict__ ws, const float* __restrict__ bb,
    float* __restrict__ out)
{
    const int i = blockIdx.x * 128 + threadIdx.x;
    float s = bb[0];
    #pragma unroll
    for (int gq = 0; gq < 16; ++gq)
        s += ws[(size_t)gq * BATCH + i];    // coalesced across threads; L2-hot
    out[i] = s;
}

extern "C" void kernel_launch(void* const* d_in, const int* in_sizes, int n_in,
                              void* d_out, int out_size, void* d_ws, size_t ws_size,
                              hipStream_t stream) {
    const float* x  = (const float*)d_in[0];
    const float* la = (const float*)d_in[1];
    const float* bb = (const float*)d_in[2];
    const float* W1 = (const float*)d_in[3];
    const float* b1 = (const float*)d_in[4];
    const float* W2 = (const float*)d_in[5];
    const float* b2 = (const float*)d_in[6];
    const float* W3 = (const float*)d_in[7];
    const float* b3 = (const float*)d_in[8];
    float* out = (float*)d_out;
    float* ws  = (float*)d_ws;

    dim3 grid(1024), block(256);   // 64 x 512-row super-blocks x 16 fg (XCD-pinned)
    hipLaunchKernelGGL(igann_kernel, grid, block, 0, stream,
                       x, la, bb, W1, b1, W2, b2, W3, b3, ws);
    hipLaunchKernelGGL(igann_reduce, dim3(256), dim3(128), 0, stream,
                       ws, bb, out);
}

// Round 8
// 105.220 us; speedup vs baseline: 2.1294x; 1.0438x over previous
//
#include <hip/hip_runtime.h>

// IGANN: per-feature 2-layer MLPs (1->16->16->1), summed over 256 features + linear term.
// R30 = R25 VERBATIM (best measured: 105.76) + one barrier removed:
//   - RESTORE round: R26 (direct-global), R28 (pk-fma), R29 (512-row dbuf) all
//     regressed; R25 is the best correct kernel. Ledger: output-path null,
//     occupancy -2.6, XCD-pin null, overlap attempts negative -> the 105.8 window
//     is fill (42.5us, its own BW roofline) + igann ~26us + fixed harness costs.
//   - Only change vs R25: sums is its own 1KB LDS array (no wbs overlay) -> the
//     mid-loop __syncthreads that guarded the alias is GONE. LDS 19456 -> 20480 B
//     = exactly 8 blocks/CU (8 x 20480 = 160 KiB). Numerics bit-identical.
//   - Pre-registered: if this lands 104.5-106.5, next round is <<ROOFLINE>>.

typedef float    f32x4 __attribute__((ext_vector_type(4)));
typedef _Float16 f16x4 __attribute__((ext_vector_type(4)));
typedef __fp16   pk16x2 __attribute__((ext_vector_type(2)));

__device__ __forceinline__ f16x4 cvt4(f32x4 v) {
    pk16x2 lo = __builtin_amdgcn_cvt_pkrtz(v[0], v[1]);
    pk16x2 hi = __builtin_amdgcn_cvt_pkrtz(v[2], v[3]);
    union { unsigned u[2]; f16x4 h; } un;
    un.u[0] = __builtin_bit_cast(unsigned, lo);
    un.u[1] = __builtin_bit_cast(unsigned, hi);
    return un.h;
}

__device__ __forceinline__ f16x4 relu_h(f16x4 v) {
    f16x4 z = {};
    return __builtin_elementwise_max(v, z);
}

__device__ __forceinline__ f32x4 relu_f(f32x4 v) {
    f32x4 z = {0.f, 0.f, 0.f, 0.f};
    return __builtin_elementwise_max(v, z);
}

#define FCHUNK 16   // features per block (16 groups of 16 = 256)
#define BATCH  32768

__global__ __launch_bounds__(256, 8) void igann_kernel(
    const float* __restrict__ x,  const float* __restrict__ la,
    const float* __restrict__ bb, const float* __restrict__ W1,
    const float* __restrict__ b1, const float* __restrict__ W2,
    const float* __restrict__ b2, const float* __restrict__ W3,
    const float* __restrict__ b3, float* __restrict__ ws)
{
    const int tid = threadIdx.x;
    const int l   = tid & 63;     // lane
    const int w   = tid >> 6;     // wave in block (0..3)
    const int r   = l & 15;       // MFMA row m (A) / col n (D)
    const int g   = l >> 4;       // k-group
    const int g4  = g * 4;

    // XCD-pinning swizzle: all 16 fg-blocks of an rb satisfy bid%8 == rb%8
    const int bid = blockIdx.x;
    const int rb  = (bid & 7) + (((bid >> 3) & 15) << 3);   // 0..127
    const int fg  = bid >> 7;                               // 0..15
    const int f0  = fg * FCHUNK;
    const int rowbase = rb * 256;

    // xs  [row][granule^((row>>2)&3)][4]  : 8192 B, conflict-free b64 frag reads
    // w2s [f][n][granule^((n>>2)&3)][4]   : 8192 B, conflict-free bfrag reads
    // wbs [f][g][w1 x4 | b1 x4] f16       : 1024 B
    // bws [f][n] -> (b2, w3) float2       : 2048 B
    // sums[row]                           : 1024 B (separate: no overlay barrier)
    __shared__ _Float16 xs [256 * 16];
    __shared__ _Float16 w2s[FCHUNK * 16 * 16];
    __shared__ _Float16 wbs[FCHUNK * 4 * 8];
    __shared__ float2   bws[FCHUNK * 16];
    __shared__ float    sums[256];              // -> 20480 B total: 8 blocks/CU exact

    // ---- stage x slice (coalesced: 4 lanes cover one 64-B row-slice) ----
    {
        const int rr  = tid >> 2;         // 0..63
        const int c4g = tid & 3;          // granule 0..3
        const int sw  = (rr >> 2) & 3;    // (row>>2)&3 — it*64 doesn't touch bits 2..3
        #pragma unroll
        for (int it = 0; it < 4; ++it) {
            const int row = it * 64 + rr;
            f32x4 v = *(const f32x4*)(x + (size_t)(rowbase + row) * 256 + f0 + c4g * 4);
            *(f16x4*)(xs + row * 16 + ((c4g ^ sw) & 3) * 4) = cvt4(v);
        }
    }
    // ---- stage W2 (thread tid owns (f,n)=(tid>>4, tid&15)) ----
    {
        const int f = tid >> 4, n = tid & 15;
        const int sw = (n >> 2) & 3;
        const float* src = W2 + ((size_t)(f0 + f) * 16 + n) * 16;
        _Float16* dst = w2s + (f * 16 + n) * 16;
        #pragma unroll
        for (int q = 0; q < 4; ++q) {
            f32x4 v = *(const f32x4*)(src + q * 4);
            *(f16x4*)(dst + ((q ^ sw) & 3) * 4) = cvt4(v);
        }
    }
    // ---- stage interleaved W1|b1 (scalar f16 stores; thread tid owns (f,k)) ----
    {
        const int f = tid >> 4, k = tid & 15;
        const int base = f * 32 + (k >> 2) * 8 + (k & 3);   // [f][g][lo4|hi4]
        wbs[base]     = (_Float16)W1[(size_t)(f0 + f) * 16 + k];
        wbs[base + 4] = (_Float16)b1[(size_t)(f0 + f) * 16 + k];
    }
    // ---- stage (b2, w3) float2 pairs ----
    {
        const int f = tid >> 4, n = tid & 15;
        bws[tid] = make_float2(b2[(size_t)(f0 + f) * 16 + n],
                               W3[(size_t)(f0 + f) * 16 + n]);
    }
    __syncthreads();

    const _Float16* xw  = xs + (w * 64 + r) * 16;
    const int       xsw = ((w * 64 + r) >> 2) & 3;          // per-lane swizzle sel
    const _Float16* w2p = w2s + r * 16 + ((g ^ ((r >> 2) & 3)) & 3) * 4;

    f32x4 acc[4];     // [tile][j]: D row g4+j (batch row within tile), col r (channel)
    #pragma unroll
    for (int t = 0; t < 4; ++t) acc[t] = (f32x4){0.f, 0.f, 0.f, 0.f};

    for (int fi = 0; fi < FCHUNK; fi += 4) {   // rolled: keeps register pressure down
        const int xoff = (((fi >> 2) ^ xsw) & 3) * 4;
        f16x4 xv[4];
        #pragma unroll
        for (int t = 0; t < 4; ++t)
            xv[t] = *(const f16x4*)(xw + t * 256 + xoff);    // t*16 rows * 16 f16

        #pragma unroll
        for (int u = 0; u < 4; ++u) {
            const int f = fi + u;
            // adjacent f16x4 reads (8 B apart) -> ds_read2_b64
            f16x4 w1h   = *(const f16x4*)(wbs + f * 32 + g * 8);
            f16x4 b1h   = *(const f16x4*)(wbs + f * 32 + g * 8 + 4);
            f16x4 bfrag = *(const f16x4*)(w2p + f * 256);
            const float2 bw = bws[f * 16 + r];          // one ds_read_b64
            const f32x4 cinit = {bw.x, bw.x, bw.x, bw.x};   // b2 folded into MFMA C
            const f32x4 w3k4  = {bw.y, bw.y, bw.y, bw.y};

            #pragma unroll
            for (int t = 0; t < 4; ++t) {
                const _Float16 s = xv[t][u];
                f16x4 xb = {s, s, s, s};
                f16x4 h = relu_h(xb * w1h + b1h);       // v_pk_fma_f16 + v_pk_max_f16
                f32x4 d = __builtin_amdgcn_mfma_f32_16x16x16f16(h, bfrag, cinit, 0, 0, 0);
                acc[t] = __builtin_elementwise_fma(relu_f(d), w3k4, acc[t]);
            }
        }
    }

    // ---- channel reduce (lane bits 0..3); r==0 lanes park sums in LDS ----
    // sums is its own buffer: no alias with wbs -> no barrier needed before writes.
    #pragma unroll
    for (int t = 0; t < 4; ++t)
        #pragma unroll
        for (int j = 0; j < 4; ++j) {
            float v = acc[t][j];
            v += __shfl_xor(v, 1, 64);
            v += __shfl_xor(v, 2, 64);
            v += __shfl_xor(v, 4, 64);
            v += __shfl_xor(v, 8, 64);
            if (r == 0)
                sums[w * 64 + t * 16 + g4 + j] = v;   // 4 lanes, stride-16B: bank-clean
        }
    __syncthreads();

    // ---- linear term + b3 partial folded in; ONE coalesced store per row ----
    float b3s = 0.f;
    #pragma unroll
    for (int c = 0; c < FCHUNK; ++c) b3s += b3[f0 + c];   // uniform -> s_loads
    float lin = 0.f;
    {
        const int swe = (tid >> 2) & 3;
        #pragma unroll
        for (int gq = 0; gq < 4; ++gq) {
            f16x4 xv4 = *(const f16x4*)(xs + tid * 16 + ((gq ^ swe) & 3) * 4);
            #pragma unroll
            for (int e = 0; e < 4; ++e)
                lin = fmaf((float)xv4[e], la[f0 + gq * 4 + e], lin);  // la uniform
        }
    }
    ws[(size_t)fg * BATCH + rowbase + tid] = sums[tid] + lin + b3s;
}

__global__ __launch_bounds__(128) void igann_reduce(
    const float* __restrict__ ws, const float* __restrict__ bb,
    float* __restrict__ out)
{
    const int i = blockIdx.x * 128 + threadIdx.x;
    float s = bb[0];
    #pragma unroll
    for (int gq = 0; gq < 16; ++gq)
        s += ws[(size_t)gq * BATCH + i];    // coalesced across threads; L2-hot
    out[i] = s;
}

extern "C" void kernel_launch(void* const* d_in, const int* in_sizes, int n_in,
                              void* d_out, int out_size, void* d_ws, size_t ws_size,
                              hipStream_t stream) {
    const float* x  = (const float*)d_in[0];
    const float* la = (const float*)d_in[1];
    const float* bb = (const float*)d_in[2];
    const float* W1 = (const float*)d_in[3];
    const float* b1 = (const float*)d_in[4];
    const float* W2 = (const float*)d_in[5];
    const float* b2 = (const float*)d_in[6];
    const float* W3 = (const float*)d_in[7];
    const float* b3 = (const float*)d_in[8];
    float* out = (float*)d_out;
    float* ws  = (float*)d_ws;

    dim3 grid(2048), block(256);   // 2048 = 8 XCD groups x 16 rb x 16 fg (swizzled)
    hipLaunchKernelGGL(igann_kernel, grid, block, 0, stream,
                       x, la, bb, W1, b1, W2, b2, W3, b3, ws);
    hipLaunchKernelGGL(igann_reduce, dim3(256), dim3(128), 0, stream,
                       ws, bb, out);
}